// Round 4
// baseline (485.520 us; speedup 1.0000x reference)
//
#include <hip/hip_runtime.h>

#define N_NODES 100000
#define N_EDGES 1600000
#define K_DIM   200
#define C_DIM   64
#define EPS_BN  1e-5f
#define NB_SCAN ((N_NODES + 255) / 256)   // 391
#define MT      128                       // gemm rows per block
#define NKB     25                        // 200 / 8 k-blocks

// ===================== GEMM: register-tiled, 128x64 block tile =============
__global__ __launch_bounds__(256) void k_gemm2(const float* __restrict__ x,
                                               const float* __restrict__ W,
                                               float* __restrict__ xw) {
    __shared__ float xT[8][MT];      // 4 KB, transposed x tile
    __shared__ float Wt[8][C_DIM];   // 2 KB
    int tid = threadIdx.x;
    int tx = tid & 15;               // col quad: c0 = tx*4
    int ty = tid >> 4;               // row octet: r0 = ty*8
    int row0 = blockIdx.x * MT;

    int lrow = tid >> 1;             // 0..127
    int lk   = (tid & 1) * 4;        // 0 or 4
    int grow = row0 + lrow;
    if (grow > N_NODES - 1) grow = N_NODES - 1;
    const float* xp = x + (size_t)grow * K_DIM + lk;
    int wk = tid >> 4;
    int wc = (tid & 15) * 4;

    float acc[8][4];
    #pragma unroll
    for (int i = 0; i < 8; ++i)
        #pragma unroll
        for (int j = 0; j < 4; ++j) acc[i][j] = 0.f;

    float4 xr = *(const float4*)xp;
    float4 wr = {0,0,0,0};
    if (tid < 128) wr = *(const float4*)(W + wk * C_DIM + wc);

    for (int kb = 0; kb < NKB; ++kb) {
        xT[lk + 0][lrow] = xr.x;
        xT[lk + 1][lrow] = xr.y;
        xT[lk + 2][lrow] = xr.z;
        xT[lk + 3][lrow] = xr.w;
        if (tid < 128) *(float4*)&Wt[wk][wc] = wr;
        __syncthreads();
        if (kb < NKB - 1) {
            xr = *(const float4*)(xp + (kb + 1) * 8);
            if (tid < 128) wr = *(const float4*)(W + ((kb + 1) * 8 + wk) * C_DIM + wc);
        }
        #pragma unroll
        for (int k = 0; k < 8; ++k) {
            float4 xa = *(const float4*)&xT[k][ty * 8];
            float4 xb = *(const float4*)&xT[k][ty * 8 + 4];
            float4 wv = *(const float4*)&Wt[k][tx * 4];
            float xv[8] = {xa.x, xa.y, xa.z, xa.w, xb.x, xb.y, xb.z, xb.w};
            #pragma unroll
            for (int i = 0; i < 8; ++i) {
                acc[i][0] = fmaf(xv[i], wv.x, acc[i][0]);
                acc[i][1] = fmaf(xv[i], wv.y, acc[i][1]);
                acc[i][2] = fmaf(xv[i], wv.z, acc[i][2]);
                acc[i][3] = fmaf(xv[i], wv.w, acc[i][3]);
            }
        }
        __syncthreads();
    }
    #pragma unroll
    for (int i = 0; i < 8; ++i) {
        int r = row0 + ty * 8 + i;
        if (r < N_NODES) {
            float4 o = {acc[i][0], acc[i][1], acc[i][2], acc[i][3]};
            *(float4*)(xw + (size_t)r * C_DIM + tx * 4) = o;
        }
    }
}

// ---------------- BN apply, float4 ----------------------------------------
__global__ void k_final4(const float4* __restrict__ h4, const float* __restrict__ stats,
                         const float* __restrict__ bnw, const float* __restrict__ bnb,
                         float4* __restrict__ out4) {
    int tid = blockIdx.x * blockDim.x + threadIdx.x;
    int stride = gridDim.x * blockDim.x;   // multiple of 16 -> q fixed
    int q = tid & 15;
    float4 scale, shift;
    {
        float s[4], f[4];
        #pragma unroll
        for (int j = 0; j < 4; ++j) {
            int c = q * 4 + j;
            float mean = stats[c] * (1.0f / N_NODES);
            float var  = stats[64 + c] * (1.0f / N_NODES) - mean * mean;
            s[j] = rsqrtf(var + EPS_BN) * bnw[c];
            f[j] = bnb[c] - mean * s[j];
        }
        scale = {s[0], s[1], s[2], s[3]};
        shift = {f[0], f[1], f[2], f[3]};
    }
    for (int i = tid; i < N_NODES * 16; i += stride) {
        float4 h = h4[i];
        float4 o;
        o.x = fmaf(h.x, scale.x, shift.x);
        o.y = fmaf(h.y, scale.y, shift.y);
        o.z = fmaf(h.z, scale.z, shift.z);
        o.w = fmaf(h.w, scale.w, shift.w);
        out4[i] = o;
    }
}

// ===================== CSR build ==========================================
__global__ void k_deg_int(const int* __restrict__ dst, int* __restrict__ deg) {
    int tid = blockIdx.x * blockDim.x + threadIdx.x;
    int stride = gridDim.x * blockDim.x;
    for (int e = tid; e < N_EDGES; e += stride)
        atomicAdd(&deg[dst[e]], 1);
}

__global__ void k_scan_block(const int* __restrict__ deg, int* __restrict__ bsum) {
    __shared__ int ls[256];
    int i = blockIdx.x * 256 + threadIdx.x;
    ls[threadIdx.x] = (i < N_NODES) ? deg[i] : 0;
    __syncthreads();
    for (int off = 128; off > 0; off >>= 1) {
        if (threadIdx.x < off) ls[threadIdx.x] += ls[threadIdx.x + off];
        __syncthreads();
    }
    if (threadIdx.x == 0) bsum[blockIdx.x] = ls[0];
}

__global__ void k_scan_top(const int* __restrict__ bsum, int* __restrict__ boff) {
    __shared__ int ls[512];
    int v = (threadIdx.x < NB_SCAN) ? bsum[threadIdx.x] : 0;
    ls[threadIdx.x] = v;
    __syncthreads();
    for (int off = 1; off < 512; off <<= 1) {
        int t = (threadIdx.x >= off) ? ls[threadIdx.x - off] : 0;
        __syncthreads();
        ls[threadIdx.x] += t;
        __syncthreads();
    }
    if (threadIdx.x < NB_SCAN) boff[threadIdx.x] = ls[threadIdx.x] - v; // exclusive
}

__global__ void k_scan_write(const int* __restrict__ deg, const int* __restrict__ boff,
                             int* __restrict__ row_start, float* __restrict__ dinv) {
    __shared__ int ls[256];
    int i = blockIdx.x * 256 + threadIdx.x;
    int v = (i < N_NODES) ? deg[i] : 0;
    ls[threadIdx.x] = v;
    __syncthreads();
    for (int off = 1; off < 256; off <<= 1) {        // inclusive scan
        int t = (threadIdx.x >= off) ? ls[threadIdx.x - off] : 0;
        __syncthreads();
        ls[threadIdx.x] += t;
        __syncthreads();
    }
    if (i < N_NODES) {
        row_start[i] = boff[blockIdx.x] + ls[threadIdx.x] - v;  // exclusive
        dinv[i] = rsqrtf((float)v + 1.0f);                      // +1 self loop
    }
    if (i == N_NODES - 1) row_start[N_NODES] = N_EDGES;
}

__global__ void k_fill(const int* __restrict__ src, const int* __restrict__ dst,
                       const int* __restrict__ row_start, int* __restrict__ cursor,
                       int* __restrict__ csr) {
    int tid = blockIdx.x * blockDim.x + threadIdx.x;
    int stride = gridDim.x * blockDim.x;
    for (int e = tid; e < N_EDGES; e += stride) {
        int d = dst[e];
        int pos = atomicAdd(&cursor[d], 1);
        csr[row_start[d] + pos] = src[e];
    }
}

// ===================== gather v3: 2 nodes/wave, staged edges, deep MLP =====
__global__ void k_gather(const int* __restrict__ csr, const int* __restrict__ row_start,
                         const float* __restrict__ dinv, const float4* __restrict__ xw4,
                         const float* __restrict__ b, float4* __restrict__ h4,
                         float* __restrict__ stats) {
    int tid = threadIdx.x;
    int lane = tid & 63;
    int g = lane >> 4;        // edge slot within step / node selector in epilogue
    int q = lane & 15;        // channel quad
    int wid = (blockIdx.x * blockDim.x + tid) >> 6;
    int nw  = (gridDim.x * blockDim.x) >> 6;
    float4 bq = ((const float4*)b)[q];
    float4 s1 = {0,0,0,0}, s2 = {0,0,0,0};

    for (int p = wid; p < N_NODES / 2; p += nw) {
        int n0 = 2 * p;
        int beg0 = row_start[n0];
        int beg1 = row_start[n0 + 1];
        int end1 = row_start[n0 + 2];
        int d0 = beg1 - beg0, d1 = end1 - beg1;
        int dm = d0 > d1 ? d0 : d1;
        float4 acc0 = {0,0,0,0}, acc1 = {0,0,0,0};

        for (int off = 0; off < dm; off += 16) {
            // lanes 0-15 stage node0's chunk, lanes 16-31 stage node1's
            int myc = 0; float mydv = 0.f;
            {
                int sl  = lane & 15;
                int sel = lane >> 4;
                if (sel < 2) {
                    int dd = sel ? d1 : d0;
                    int bb = sel ? beg1 : beg0;
                    if (off + sl < dd) { myc = csr[bb + off + sl]; mydv = dinv[myc]; }
                }
            }
            #pragma unroll
            for (int t = 0; t < 4; ++t) {
                int idx = g + 4 * t;
                int   sA = __shfl(myc,  idx);
                float vA = __shfl(mydv, idx);
                int   sB = __shfl(myc,  idx + 16);
                float vB = __shfl(mydv, idx + 16);
                float4 xA = xw4[(size_t)sA * 16 + q];
                float4 xB = xw4[(size_t)sB * 16 + q];
                acc0.x = fmaf(vA, xA.x, acc0.x);
                acc0.y = fmaf(vA, xA.y, acc0.y);
                acc0.z = fmaf(vA, xA.z, acc0.z);
                acc0.w = fmaf(vA, xA.w, acc0.w);
                acc1.x = fmaf(vB, xB.x, acc1.x);
                acc1.y = fmaf(vB, xB.y, acc1.y);
                acc1.z = fmaf(vB, xB.z, acc1.z);
                acc1.w = fmaf(vB, xB.w, acc1.w);
            }
        }
        // butterfly over the 4 edge-groups (lane bits 4,5)
        #pragma unroll
        for (int m = 16; m <= 32; m <<= 1) {
            acc0.x += __shfl_xor(acc0.x, m); acc0.y += __shfl_xor(acc0.y, m);
            acc0.z += __shfl_xor(acc0.z, m); acc0.w += __shfl_xor(acc0.w, m);
            acc1.x += __shfl_xor(acc1.x, m); acc1.y += __shfl_xor(acc1.y, m);
            acc1.z += __shfl_xor(acc1.z, m); acc1.w += __shfl_xor(acc1.w, m);
        }
        if (g < 2) {
            int nn = n0 + g;
            float4 acc = g ? acc1 : acc0;
            float dn = dinv[nn];
            float4 xs = xw4[(size_t)nn * 16 + q];
            float4 hv;
            hv.x = fmaxf(fmaf(dn, fmaf(dn, xs.x, acc.x), bq.x), 0.f);
            hv.y = fmaxf(fmaf(dn, fmaf(dn, xs.y, acc.y), bq.y), 0.f);
            hv.z = fmaxf(fmaf(dn, fmaf(dn, xs.z, acc.z), bq.z), 0.f);
            hv.w = fmaxf(fmaf(dn, fmaf(dn, xs.w, acc.w), bq.w), 0.f);
            h4[(size_t)nn * 16 + q] = hv;
            s1.x += hv.x; s1.y += hv.y; s1.z += hv.z; s1.w += hv.w;
            s2.x = fmaf(hv.x, hv.x, s2.x); s2.y = fmaf(hv.y, hv.y, s2.y);
            s2.z = fmaf(hv.z, hv.z, s2.z); s2.w = fmaf(hv.w, hv.w, s2.w);
        }
    }

    __shared__ float4 l1[256], l2[256];
    l1[tid] = s1; l2[tid] = s2;
    __syncthreads();
    if (tid < 16) {   // tid == q
        float4 t1 = {0,0,0,0}, t2 = {0,0,0,0};
        #pragma unroll
        for (int w = 0; w < 8; ++w) {
            int li = (w >> 1) * 64 + (w & 1) * 16 + tid;
            float4 a = l1[li], e = l2[li];
            t1.x += a.x; t1.y += a.y; t1.z += a.z; t1.w += a.w;
            t2.x += e.x; t2.y += e.y; t2.z += e.z; t2.w += e.w;
        }
        unsafeAtomicAdd(&stats[tid * 4 + 0], t1.x);
        unsafeAtomicAdd(&stats[tid * 4 + 1], t1.y);
        unsafeAtomicAdd(&stats[tid * 4 + 2], t1.z);
        unsafeAtomicAdd(&stats[tid * 4 + 3], t1.w);
        unsafeAtomicAdd(&stats[64 + tid * 4 + 0], t2.x);
        unsafeAtomicAdd(&stats[64 + tid * 4 + 1], t2.y);
        unsafeAtomicAdd(&stats[64 + tid * 4 + 2], t2.z);
        unsafeAtomicAdd(&stats[64 + tid * 4 + 3], t2.w);
    }
}

// ===========================================================================
extern "C" void kernel_launch(void* const* d_in, const int* in_sizes, int n_in,
                              void* d_out, int out_size, void* d_ws, size_t ws_size,
                              hipStream_t stream) {
    const float* x   = (const float*)d_in[0];
    const int*   ei  = (const int*)d_in[1];
    const float* W   = (const float*)d_in[2];
    const float* b   = (const float*)d_in[3];
    const float* bnw = (const float*)d_in[4];
    const float* bnb = (const float*)d_in[5];
    float* out = (float*)d_out;

    const int* src = ei;
    const int* dst = ei + N_EDGES;
    char* ws = (char*)d_ws;

    const size_t SZ_I = 400128;                 // 100000*4 padded
    const size_t OFF_CUR  = SZ_I;
    const size_t OFF_STAT = 2 * SZ_I;
    const size_t OFF_DINV = 2 * SZ_I + 512;
    const size_t OFF_ROW  = 3 * SZ_I + 512;
    const size_t OFF_BSUM = 4 * SZ_I + 512;
    const size_t OFF_BOFF = 4 * SZ_I + 2560;
    const size_t OFF_CSR  = 4 * SZ_I + 4608;
    const size_t OFF_H    = OFF_CSR + (size_t)N_EDGES * 4;
    const size_t NEEDED   = OFF_H + (size_t)N_NODES * C_DIM * 4;

    float* xw = out;   // xw lives in d_out until k_final4 overwrites it
    const int GEMM_GRID = (N_NODES + MT - 1) / MT;   // 782

    int*   deg       = (int*)ws;
    int*   cursor    = (int*)(ws + OFF_CUR);
    float* stats     = (float*)(ws + OFF_STAT);
    float* dinv      = (float*)(ws + OFF_DINV);
    int*   row_start = (int*)(ws + OFF_ROW);
    int*   bsum      = (int*)(ws + OFF_BSUM);
    int*   boff      = (int*)(ws + OFF_BOFF);
    int*   csr       = (int*)(ws + OFF_CSR);
    float* h         = (float*)(ws + OFF_H);

    hipMemsetAsync(d_ws, 0, OFF_STAT + 512, stream);  // deg, cursor, stats

    k_deg_int   <<<2048, 256, 0, stream>>>(dst, deg);
    k_scan_block<<<NB_SCAN, 256, 0, stream>>>(deg, bsum);
    k_scan_top  <<<1, 512, 0, stream>>>(bsum, boff);
    k_scan_write<<<NB_SCAN, 256, 0, stream>>>(deg, boff, row_start, dinv);
    k_fill      <<<2048, 256, 0, stream>>>(src, dst, row_start, cursor, csr);
    k_gemm2     <<<GEMM_GRID, 256, 0, stream>>>(x, W, xw);
    k_gather    <<<2048, 256, 0, stream>>>(csr, row_start, dinv,
                                           (const float4*)xw, b, (float4*)h, stats);
    k_final4    <<<2048, 256, 0, stream>>>((const float4*)h, stats, bnw, bnb,
                                           (float4*)out);
    (void)ws_size; (void)NEEDED;
}